// Round 1
// baseline (57.349 us; speedup 1.0000x reference)
//
#include <hip/hip_runtime.h>

#define N_STATES 12
#define MAX_OBS 50
#define TABLE_SIZE (N_STATES * MAX_OBS)  // 600 entries

// Kernel 1: build the 600-entry log-prob table in double precision.
// lp(s, o) = m*log(phi/(m+phi)) + o*log(m/(m+phi)) + lgamma(o+m) - lgamma(o+1) - lgamma(m)
__global__ void build_table_kernel(const float* __restrict__ state_means,
                                   const float* __restrict__ state_phis,
                                   float* __restrict__ table) {
    int t = blockIdx.x * blockDim.x + threadIdx.x;
    if (t >= TABLE_SIZE) return;
    int s = t / MAX_OBS;
    int o = t % MAX_OBS;
    double m  = (double)state_means[s];
    double ph = (double)state_phis[s];
    double ob = (double)o;
    double log_denom = log(m + ph);
    double log_p   = log(m)  - log_denom;
    double log_1mp = log(ph) - log_denom;
    double lp = m * log_1mp + ob * log_p
              + lgamma(ob + m) - lgamma(ob + 1.0) - lgamma(m);
    table[t] = (float)lp;
}

// Kernel 2: stream obs+states, table-lookup in LDS, hierarchical sum.
__global__ void __launch_bounds__(256) nb_sum_kernel(const float* __restrict__ obs,
                                                     const int* __restrict__ states,
                                                     const float* __restrict__ table,
                                                     float* __restrict__ out,
                                                     int n) {
    __shared__ float lut[TABLE_SIZE];
    for (int i = threadIdx.x; i < TABLE_SIZE; i += blockDim.x)
        lut[i] = table[i];
    __syncthreads();

    float acc = 0.0f;
    const int tid = blockIdx.x * blockDim.x + threadIdx.x;
    const int nthreads = gridDim.x * blockDim.x;
    const int n4 = n >> 2;
    const float4* __restrict__ obs4 = (const float4*)obs;
    const int4*  __restrict__ st4  = (const int4*)states;

    for (int i = tid; i < n4; i += nthreads) {
        float4 o = obs4[i];
        int4   s = st4[i];
        acc += lut[s.x * MAX_OBS + (int)o.x];
        acc += lut[s.y * MAX_OBS + (int)o.y];
        acc += lut[s.z * MAX_OBS + (int)o.z];
        acc += lut[s.w * MAX_OBS + (int)o.w];
    }
    // tail (n not multiple of 4)
    for (int i = (n4 << 2) + tid; i < n; i += nthreads)
        acc += lut[states[i] * MAX_OBS + (int)obs[i]];

    // wave64 butterfly reduce
    #pragma unroll
    for (int off = 32; off > 0; off >>= 1)
        acc += __shfl_down(acc, off, 64);

    __shared__ float wsum[4];  // 256 threads / 64 lanes
    const int lane = threadIdx.x & 63;
    const int wid  = threadIdx.x >> 6;
    if (lane == 0) wsum[wid] = acc;
    __syncthreads();
    if (threadIdx.x == 0) {
        float s = wsum[0] + wsum[1] + wsum[2] + wsum[3];
        atomicAdd(out, s);
    }
}

extern "C" void kernel_launch(void* const* d_in, const int* in_sizes, int n_in,
                              void* d_out, int out_size, void* d_ws, size_t ws_size,
                              hipStream_t stream) {
    const float* obs        = (const float*)d_in[0];
    const int*   states     = (const int*)d_in[1];
    const float* state_means = (const float*)d_in[2];
    const float* state_phis  = (const float*)d_in[3];
    float* out   = (float*)d_out;
    float* table = (float*)d_ws;
    const int n = in_sizes[0];

    // d_out is poisoned (0xAA) before timing and never re-poisoned between
    // replays -> zero it every call, on-stream (graph-capture safe).
    hipMemsetAsync(out, 0, sizeof(float), stream);

    build_table_kernel<<<dim3((TABLE_SIZE + 255) / 256), dim3(256), 0, stream>>>(
        state_means, state_phis, table);

    // 2048 blocks x 256 threads = 524288 threads; 16.7M/4 vec4-iters -> 8 per thread.
    nb_sum_kernel<<<dim3(2048), dim3(256), 0, stream>>>(obs, states, table, out, n);
}

// Round 2
// 50.182 us; speedup vs baseline: 1.1428x; 1.1428x over previous
//
#include <hip/hip_runtime.h>

#define N_STATES 12
#define MAX_OBS 50
#define TABLE_SIZE (N_STATES * MAX_OBS)  // 600 entries

// Kernel 1: build the 600-entry log-prob table in double precision.
// lp(s, o) = m*log(phi/(m+phi)) + o*log(m/(m+phi)) + lgamma(o+m) - lgamma(o+1) - lgamma(m)
__global__ void build_table_kernel(const float* __restrict__ state_means,
                                   const float* __restrict__ state_phis,
                                   float* __restrict__ table) {
    int t = blockIdx.x * blockDim.x + threadIdx.x;
    if (t >= TABLE_SIZE) return;
    int s = t / MAX_OBS;
    int o = t % MAX_OBS;
    double m  = (double)state_means[s];
    double ph = (double)state_phis[s];
    double ob = (double)o;
    double log_denom = log(m + ph);
    double log_p   = log(m)  - log_denom;
    double log_1mp = log(ph) - log_denom;
    double lp = m * log_1mp + ob * log_p
              + lgamma(ob + m) - lgamma(ob + 1.0) - lgamma(m);
    table[t] = (float)lp;
}

// Kernel 2: stream obs+states with deep MLP (unroll-4 load batches),
// LDS table lookup, hierarchical sum.
__global__ void __launch_bounds__(256) nb_sum_kernel(const float* __restrict__ obs,
                                                     const int* __restrict__ states,
                                                     const float* __restrict__ table,
                                                     float* __restrict__ out,
                                                     int n) {
    __shared__ float lut[TABLE_SIZE];
    for (int i = threadIdx.x; i < TABLE_SIZE; i += blockDim.x)
        lut[i] = table[i];
    __syncthreads();

    float acc = 0.0f;
    const int tid = blockIdx.x * blockDim.x + threadIdx.x;
    const int nthreads = gridDim.x * blockDim.x;
    const int n4 = n >> 2;
    const float4* __restrict__ obs4 = (const float4*)obs;
    const int4*  __restrict__ st4  = (const int4*)states;

    if (n4 == (nthreads << 3)) {
        // Fast path: exactly 8 vec4 elements per thread -> 2 batches of 4.
        // Each batch issues 8 global_load_dwordx4 (128 B/lane in flight)
        // before any dependent LDS lookup.
        int base = tid;
        #pragma unroll
        for (int outer = 0; outer < 2; ++outer) {
            float4 o[4];
            int4   s[4];
            #pragma unroll
            for (int k = 0; k < 4; ++k) {
                int idx = base + k * nthreads;
                o[k] = obs4[idx];
                s[k] = st4[idx];
            }
            #pragma unroll
            for (int k = 0; k < 4; ++k) {
                acc += lut[s[k].x * MAX_OBS + (int)o[k].x];
                acc += lut[s[k].y * MAX_OBS + (int)o[k].y];
                acc += lut[s[k].z * MAX_OBS + (int)o[k].z];
                acc += lut[s[k].w * MAX_OBS + (int)o[k].w];
            }
            base += 4 * nthreads;
        }
    } else {
        // Generic path (kept for robustness; not hit at N=16777216/2048x256).
        for (int i = tid; i < n4; i += nthreads) {
            float4 o = obs4[i];
            int4   s = st4[i];
            acc += lut[s.x * MAX_OBS + (int)o.x];
            acc += lut[s.y * MAX_OBS + (int)o.y];
            acc += lut[s.z * MAX_OBS + (int)o.z];
            acc += lut[s.w * MAX_OBS + (int)o.w];
        }
        for (int i = (n4 << 2) + tid; i < n; i += nthreads)
            acc += lut[states[i] * MAX_OBS + (int)obs[i]];
    }

    // wave64 butterfly reduce
    #pragma unroll
    for (int off = 32; off > 0; off >>= 1)
        acc += __shfl_down(acc, off, 64);

    __shared__ float wsum[4];  // 256 threads / 64 lanes
    const int lane = threadIdx.x & 63;
    const int wid  = threadIdx.x >> 6;
    if (lane == 0) wsum[wid] = acc;
    __syncthreads();
    if (threadIdx.x == 0) {
        float s = wsum[0] + wsum[1] + wsum[2] + wsum[3];
        atomicAdd(out, s);
    }
}

extern "C" void kernel_launch(void* const* d_in, const int* in_sizes, int n_in,
                              void* d_out, int out_size, void* d_ws, size_t ws_size,
                              hipStream_t stream) {
    const float* obs         = (const float*)d_in[0];
    const int*   states      = (const int*)d_in[1];
    const float* state_means = (const float*)d_in[2];
    const float* state_phis  = (const float*)d_in[3];
    float* out   = (float*)d_out;
    float* table = (float*)d_ws;
    const int n = in_sizes[0];

    // d_out is poisoned (0xAA) before timing and never re-poisoned between
    // replays -> zero it every call, on-stream (graph-capture safe).
    hipMemsetAsync(out, 0, sizeof(float), stream);

    build_table_kernel<<<dim3((TABLE_SIZE + 255) / 256), dim3(256), 0, stream>>>(
        state_means, state_phis, table);

    nb_sum_kernel<<<dim3(2048), dim3(256), 0, stream>>>(obs, states, table, out, n);
}